// Round 7
// baseline (239.820 us; speedup 1.0000x reference)
//
#include <hip/hip_runtime.h>

// B=4, N=1024, C=256, H=8.
// Reference math collapses: softmax over m sums to 1, and the final einsum
// 'bnmh,bnih->bnih' contracts only m of alpha -> out = vh elementwise.
// So: out[b,n,:] = linear_output^T @ flatten_ih(V-proj(v[b,n,:]) + bias_V)
// Precompose W[j'][j] = sum_{k=i*H+h} V[i,j',h] * L[k,j]  (256x256),
// bvec[j] = sum_k bias_V_flat[k] * L[k,j], then out = v @ W + bvec.
//
// History: R0 225.4 / R10 control (byte-identical) 227.7 -> noise band is
// +-2 us. R6/R8/R9 (241-247) were REAL regressions; all three shared the
// R6-form compose_w whose bias re-walk is a serial 128-iter L2-latency
// loop on one wave (~10 us critical-path tail). R0's compose fuses bias
// into the main loop for free -> compose_w kept byte-identical here.
// R11 surgical change (apply_w only): thread = 2 cols (j, j+128) x 4 rows
// instead of 1 col x 8 rows. Per jp-quad: 4 ds_read_b128 (was 8) + 8
// scalar W dwords (proven lane-coalesced L1-hot path) + 32 fmacs ->
// LDS issue halved; occupancy/LDS-size/grid/W-path unchanged.

#define ROWS 8     // rows per block in apply kernel

// Kernel 1: split-K GEMM composing W and bvec into workspace (atomicAdd).
// grid = (16 k-chunks of 128, 16 j'-tiles of 16), block = 256 (j).
__global__ __launch_bounds__(256) void compose_w(
    const float* __restrict__ V,    // [C, C, H] : V[i*2048 + j'*8 + h]
    const float* __restrict__ bV,   // [C, H] flat = [2048]
    const float* __restrict__ L,    // [2048, 256]
    float* __restrict__ W2,         // [256*256] (zeroed)
    float* __restrict__ bvec)       // [256] (zeroed)
{
    const int j   = threadIdx.x;
    const int k0  = blockIdx.x * 128;
    const int jp0 = blockIdx.y * 16;

    __shared__ float sV[128 * 16];  // sV[kk][r] = Vr[k0+kk][jp0+r]
    __shared__ float sb[128];

    for (int e = threadIdx.x; e < 128 * 16; e += 256) {
        const int kk = e >> 4, r = e & 15;
        const int k = k0 + kk;
        sV[e] = V[(k >> 3) * 2048 + (jp0 + r) * 8 + (k & 7)];
    }
    if (threadIdx.x < 128) sb[threadIdx.x] = bV[k0 + threadIdx.x];
    __syncthreads();

    float acc[16];
#pragma unroll
    for (int r = 0; r < 16; ++r) acc[r] = 0.f;
    float accb = 0.f;

    const float* Lp = L + k0 * 256 + j;
    for (int kk = 0; kk < 128; ++kk) {
        const float lv = Lp[kk * 256];          // coalesced, L2-resident
        accb += sb[kk] * lv;
#pragma unroll
        for (int r = 0; r < 16; ++r) acc[r] += sV[kk * 16 + r] * lv;  // LDS broadcast
    }
#pragma unroll
    for (int r = 0; r < 16; ++r)
        atomicAdd(&W2[(jp0 + r) * 256 + j], acc[r]);
    if (blockIdx.y == 0) atomicAdd(&bvec[j], accb);
}

// Kernel 2: out[row][j] = bvec[j] + sum_j' v[row][j'] * W2[j'][j]
// grid = 4096/ROWS blocks, block = 256. Thread t: cols j1 = t&127 and
// j2 = j1+128; rows r0 = row0 + 4*(t>>7) .. +3. Per jp-quad: 4 LDS b128
// (same-address broadcast within wave, conflict-free) + 8 coalesced W
// dwords (L1-hot: all 512 blocks stream the same 256KB W2) + 32 fmacs.
__global__ __launch_bounds__(256) void apply_w(
    const float* __restrict__ v,    // [4096, 256]
    const float* __restrict__ W2,   // [256, 256]
    const float* __restrict__ bvec, // [256]
    float* __restrict__ out)        // [4096, 256]
{
    const int t    = threadIdx.x;
    const int row0 = blockIdx.x * ROWS;
    const int j1   = t & 127;
    const int j2   = j1 + 128;
    const int rg   = t >> 7;              // 0..1
    const int r0   = row0 + 4 * rg;

    __shared__ float sv[ROWS * 256];
    // float4 staging: ROWS*256 floats = ROWS*64 float4s, coalesced dwordx4
    {
        const float4* v4 = reinterpret_cast<const float4*>(v + row0 * 256);
        float4* sv4 = reinterpret_cast<float4*>(sv);
#pragma unroll
        for (int e = t; e < ROWS * 64; e += 256)
            sv4[e] = v4[e];
    }
    __syncthreads();

    const float b1 = bvec[j1];
    const float b2 = bvec[j2];
    float acc1[4], acc2[4];
#pragma unroll
    for (int r = 0; r < 4; ++r) { acc1[r] = b1; acc2[r] = b2; }

    const float* Wa = W2 + j1;
    const float* Wb = W2 + j2;
    const float* svr = sv + 4 * rg * 256;

    for (int jp = 0; jp < 256; jp += 4) {
        // 8 coalesced, L1/L2-resident W reads (independent -> overlapped)
        const float wa0 = Wa[(jp + 0) * 256];
        const float wa1 = Wa[(jp + 1) * 256];
        const float wa2 = Wa[(jp + 2) * 256];
        const float wa3 = Wa[(jp + 3) * 256];
        const float wb0 = Wb[(jp + 0) * 256];
        const float wb1 = Wb[(jp + 1) * 256];
        const float wb2 = Wb[(jp + 2) * 256];
        const float wb3 = Wb[(jp + 3) * 256];
#pragma unroll
        for (int r = 0; r < 4; ++r) {
            const float4 s = *reinterpret_cast<const float4*>(&svr[r * 256 + jp]);  // ds_read_b128 broadcast
            acc1[r] += s.x * wa0 + s.y * wa1 + s.z * wa2 + s.w * wa3;
            acc2[r] += s.x * wb0 + s.y * wb1 + s.z * wb2 + s.w * wb3;
        }
    }
#pragma unroll
    for (int r = 0; r < 4; ++r) {
        out[(r0 + r) * 256 + j1] = acc1[r];
        out[(r0 + r) * 256 + j2] = acc2[r];
    }
}

extern "C" void kernel_launch(void* const* d_in, const int* in_sizes, int n_in,
                              void* d_out, int out_size, void* d_ws, size_t ws_size,
                              hipStream_t stream) {
    // setup_inputs order: q(0) k(1) v(2) bias(3) atten_mask(4) Q(5) K(6) V(7)
    //                     bias_Q(8) bias_K(9) bias_V(10) linear_output(11)
    const float* v_in = (const float*)d_in[2];
    const float* V_w  = (const float*)d_in[7];
    const float* bV   = (const float*)d_in[10];
    const float* L    = (const float*)d_in[11];

    float* W2   = (float*)d_ws;           // 256*256 floats
    float* bvec = W2 + 256 * 256;         // 256 floats

    hipMemsetAsync(d_ws, 0, (256 * 256 + 256) * sizeof(float), stream);
    compose_w<<<dim3(16, 16), 256, 0, stream>>>(V_w, bV, L, W2, bvec);
    apply_w<<<4096 / ROWS, 256, 0, stream>>>(v_in, W2, bvec, (float*)d_out);
}

// Round 8
// 230.421 us; speedup vs baseline: 1.0408x; 1.0408x over previous
//
#include <hip/hip_runtime.h>
#include <hip/hip_fp16.h>

// B=4, N=1024, C=256, H=8.
// Reference math collapses: softmax over m sums to 1, and the final einsum
// 'bnmh,bnih->bnih' contracts only m of alpha -> out = vh elementwise.
// So: out[b,n,:] = linear_output^T @ flatten_ih(V-proj(v[b,n,:]) + bias_V)
// Precompose W[j'][j] = sum_{k=i*H+h} V[i,j',h] * L[k,j]  (256x256),
// bvec[j] = sum_k bias_V_flat[k] * L[k,j], then out = v @ W + bvec.
//
// Ledger: R0 225.4 / R10 control 227.7 (noise +-2). R5 281.6 (scalarize
// FAIL). R6 247.2 / R8 243.3 / R9 241.4 (restructures, FAIL). R11 239.8:
// halved LDS, but cross-wave duplicate W reads doubled the L2 W-stream ->
// +12 us. Unified model: apply_w is bound by the W2 L2->L1 stream
// (512 blocks x 256 KB = 128 MB @ ~10.7 TB/s ~= 12 us); LDS broadcasts
// ~4cyc (same-address) ~= 7 us and VMEM issue ~3 us hide under it.
// R12: halve W-stream BYTES. W packed as f16 pairs along jp ( |W|<~0.2,
// f16 rel-err 5e-4 -> delta-out ~2e-3 << 0.0156 current absmax ).
// compose_w byte-identical (proven); new convert_w packs f32 W2 ->
// __half2 Wh[128][256]; apply_w keeps R0 loop shape: per jp-quad now
// 2 packed dword loads + 4 cvt + 8 LDS broadcast b128 + 32 fmac.
// W L2 traffic 128 -> 64 MB, W VMEM insts halved. +1 tiny launch.

#define ROWS 8     // rows per block in apply kernel

// Kernel 1: split-K GEMM composing W and bvec into workspace (atomicAdd).
// grid = (16 k-chunks of 128, 16 j'-tiles of 16), block = 256 (j).
__global__ __launch_bounds__(256) void compose_w(
    const float* __restrict__ V,    // [C, C, H] : V[i*2048 + j'*8 + h]
    const float* __restrict__ bV,   // [C, H] flat = [2048]
    const float* __restrict__ L,    // [2048, 256]
    float* __restrict__ W2,         // [256*256] (zeroed)
    float* __restrict__ bvec)       // [256] (zeroed)
{
    const int j   = threadIdx.x;
    const int k0  = blockIdx.x * 128;
    const int jp0 = blockIdx.y * 16;

    __shared__ float sV[128 * 16];  // sV[kk][r] = Vr[k0+kk][jp0+r]
    __shared__ float sb[128];

    for (int e = threadIdx.x; e < 128 * 16; e += 256) {
        const int kk = e >> 4, r = e & 15;
        const int k = k0 + kk;
        sV[e] = V[(k >> 3) * 2048 + (jp0 + r) * 8 + (k & 7)];
    }
    if (threadIdx.x < 128) sb[threadIdx.x] = bV[k0 + threadIdx.x];
    __syncthreads();

    float acc[16];
#pragma unroll
    for (int r = 0; r < 16; ++r) acc[r] = 0.f;
    float accb = 0.f;

    const float* Lp = L + k0 * 256 + j;
    for (int kk = 0; kk < 128; ++kk) {
        const float lv = Lp[kk * 256];          // coalesced, L2-resident
        accb += sb[kk] * lv;
#pragma unroll
        for (int r = 0; r < 16; ++r) acc[r] += sV[kk * 16 + r] * lv;  // LDS broadcast
    }
#pragma unroll
    for (int r = 0; r < 16; ++r)
        atomicAdd(&W2[(jp0 + r) * 256 + j], acc[r]);
    if (blockIdx.y == 0) atomicAdd(&bvec[j], accb);
}

// Kernel 1b: pack W2 f32 [256][256] -> Wh __half2 [128 jp-pairs][256 j].
// grid = 128 (p), block = 256 (j); fully coalesced read/write, ~1 us.
__global__ __launch_bounds__(256) void convert_w(
    const float* __restrict__ W2,
    __half2* __restrict__ Wh)
{
    const int j = threadIdx.x;
    const int p = blockIdx.x;                    // jp-pair index 0..127
    const float a = W2[(2 * p + 0) * 256 + j];
    const float b = W2[(2 * p + 1) * 256 + j];
    Wh[p * 256 + j] = __floats2half2_rn(a, b);
}

// Kernel 2: out[row][j] = bvec[j] + sum_j' v[row][j'] * W[j'][j]
// grid = 4096/ROWS blocks, block = 256 (j). Identical structure to R0;
// W path now packed f16: per jp-quad 2 coalesced dword loads (f16x2) +
// 4 cvt + 8 ds_read_b128 broadcasts + 32 fmacs.
__global__ __launch_bounds__(256) void apply_w(
    const float* __restrict__ v,    // [4096, 256]
    const __half2* __restrict__ Wh, // [128, 256] packed (jp-pair, j)
    const float* __restrict__ bvec, // [256]
    float* __restrict__ out)        // [4096, 256]
{
    const int j = threadIdx.x;
    const int row0 = blockIdx.x * ROWS;

    __shared__ float sv[ROWS * 256];
    // float4 staging: ROWS*256 floats = ROWS*64 float4s, coalesced dwordx4
    {
        const float4* v4 = reinterpret_cast<const float4*>(v + row0 * 256);
        float4* sv4 = reinterpret_cast<float4*>(sv);
#pragma unroll
        for (int e = threadIdx.x; e < ROWS * 64; e += 256)
            sv4[e] = v4[e];
    }
    __syncthreads();

    const float b = bvec[j];
    float acc[ROWS];
#pragma unroll
    for (int r = 0; r < ROWS; ++r) acc[r] = b;

    const __half2* Wp = Wh + j;
    for (int p = 0; p < 128; p += 2) {           // jp = 2p .. 2p+3
        const __half2 h01 = Wp[(p + 0) * 256];   // W[2p][j],   W[2p+1][j]
        const __half2 h23 = Wp[(p + 1) * 256];   // W[2p+2][j], W[2p+3][j]
        const float w0 = __low2float(h01);
        const float w1 = __high2float(h01);
        const float w2 = __low2float(h23);
        const float w3 = __high2float(h23);
        const int jp = 2 * p;
#pragma unroll
        for (int r = 0; r < ROWS; ++r) {
            const float4 s = *reinterpret_cast<const float4*>(&sv[r * 256 + jp]);  // ds_read_b128 broadcast
            acc[r] += s.x * w0 + s.y * w1 + s.z * w2 + s.w * w3;
        }
    }
#pragma unroll
    for (int r = 0; r < ROWS; ++r)
        out[(row0 + r) * 256 + j] = acc[r];
}

extern "C" void kernel_launch(void* const* d_in, const int* in_sizes, int n_in,
                              void* d_out, int out_size, void* d_ws, size_t ws_size,
                              hipStream_t stream) {
    // setup_inputs order: q(0) k(1) v(2) bias(3) atten_mask(4) Q(5) K(6) V(7)
    //                     bias_Q(8) bias_K(9) bias_V(10) linear_output(11)
    const float* v_in = (const float*)d_in[2];
    const float* V_w  = (const float*)d_in[7];
    const float* bV   = (const float*)d_in[10];
    const float* L    = (const float*)d_in[11];

    float*   W2   = (float*)d_ws;                 // 64K f32
    float*   bvec = W2 + 256 * 256;               // 256 f32
    __half2* Wh   = (__half2*)(bvec + 256);       // 32K half2 (128 KB), 4B-aligned

    hipMemsetAsync(d_ws, 0, (256 * 256 + 256) * sizeof(float), stream);
    compose_w<<<dim3(16, 16), 256, 0, stream>>>(V_w, bV, L, W2, bvec);
    convert_w<<<128, 256, 0, stream>>>(W2, Wh);
    apply_w<<<4096 / ROWS, 256, 0, stream>>>(v_in, Wh, bvec, (float*)d_out);
}

// Round 9
// 228.284 us; speedup vs baseline: 1.0505x; 1.0094x over previous
//
#include <hip/hip_runtime.h>

// B=4, N=1024, C=256, H=8.
// Reference math collapses: softmax over m sums to 1, and the final einsum
// 'bnmh,bnih->bnih' contracts only m of alpha -> out = vh elementwise.
// So: out[b,n,:] = linear_output^T @ flatten_ih(V-proj(v[b,n,:]) + bias_V)
// Precompose W[j'][j] = sum_{k=i*H+h} V[i,j',h] * L[k,j]  (256x256),
// bvec[j] = sum_k bias_V_flat[k] * L[k,j], then out = v @ W + bvec.
//
// R13 = FINAL REVERT to the empirical optimum (R0 structure).
// Ledger: R0 225.4 / R10 control 227.7 (noise +-2 us; fills 77-78 us
// every round). Six structural variants all regressed:
//   R5  281.6  scalarize-uniform (hipcc emits per-lane VMEM)
//   R6  247.2  reg-tile, W float4 stream
//   R8  243.3  W-in-LDS 64KB (1 blk/CU, latency-bound)
//   R9  241.4  hybrid reg-tile 2 blk/CU
//   R11 239.8  2 cols/thread (2x W insts, cross-wave L1 dup)
//   R12 230.4  f16-packed W, +1 dispatch (W L2 bytes NOT the bottleneck)
// Conclusion: ~156 us = harness fills, ~2-3 us per dispatch slot, and
// this 3-dispatch pipeline's ~15 us of kernel time is balanced across
// LDS-broadcast/VMEM/VALU -- a local optimum robust against six
// independent perturbation directions. This config is the keeper.

#define ROWS 8     // rows per block in apply kernel

// Kernel 1: split-K GEMM composing W and bvec into workspace (atomicAdd).
// grid = (16 k-chunks of 128, 16 j'-tiles of 16), block = 256 (j).
__global__ __launch_bounds__(256) void compose_w(
    const float* __restrict__ V,    // [C, C, H] : V[i*2048 + j'*8 + h]
    const float* __restrict__ bV,   // [C, H] flat = [2048]
    const float* __restrict__ L,    // [2048, 256]
    float* __restrict__ W2,         // [256*256] (zeroed)
    float* __restrict__ bvec)       // [256] (zeroed)
{
    const int j   = threadIdx.x;
    const int k0  = blockIdx.x * 128;
    const int jp0 = blockIdx.y * 16;

    __shared__ float sV[128 * 16];  // sV[kk][r] = Vr[k0+kk][jp0+r]
    __shared__ float sb[128];

    for (int e = threadIdx.x; e < 128 * 16; e += 256) {
        const int kk = e >> 4, r = e & 15;
        const int k = k0 + kk;
        sV[e] = V[(k >> 3) * 2048 + (jp0 + r) * 8 + (k & 7)];
    }
    if (threadIdx.x < 128) sb[threadIdx.x] = bV[k0 + threadIdx.x];
    __syncthreads();

    float acc[16];
#pragma unroll
    for (int r = 0; r < 16; ++r) acc[r] = 0.f;
    float accb = 0.f;

    const float* Lp = L + k0 * 256 + j;
    for (int kk = 0; kk < 128; ++kk) {
        const float lv = Lp[kk * 256];          // coalesced, L2-resident
        accb += sb[kk] * lv;
#pragma unroll
        for (int r = 0; r < 16; ++r) acc[r] += sV[kk * 16 + r] * lv;  // LDS broadcast
    }
#pragma unroll
    for (int r = 0; r < 16; ++r)
        atomicAdd(&W2[(jp0 + r) * 256 + j], acc[r]);
    if (blockIdx.y == 0) atomicAdd(&bvec[j], accb);
}

// Kernel 2: out[row][j] = bvec[j] + sum_j' v[row][j'] * W2[j'][j]
// grid = 4096/ROWS blocks, block = 256 (j).
__global__ __launch_bounds__(256) void apply_w(
    const float* __restrict__ v,    // [4096, 256]
    const float* __restrict__ W2,   // [256, 256]
    const float* __restrict__ bvec, // [256]
    float* __restrict__ out)        // [4096, 256]
{
    const int j = threadIdx.x;
    const int row0 = blockIdx.x * ROWS;

    __shared__ float sv[ROWS * 256];
    // float4 staging: ROWS*256 floats = ROWS*64 float4s, coalesced dwordx4
    {
        const float4* v4 = reinterpret_cast<const float4*>(v + row0 * 256);
        float4* sv4 = reinterpret_cast<float4*>(sv);
#pragma unroll
        for (int e = threadIdx.x; e < ROWS * 64; e += 256)
            sv4[e] = v4[e];
    }
    __syncthreads();

    const float b = bvec[j];
    float acc[ROWS];
#pragma unroll
    for (int r = 0; r < ROWS; ++r) acc[r] = b;

    const float* Wp = W2 + j;
    for (int jp = 0; jp < 256; jp += 4) {
        // 4 coalesced, L2-resident W reads (independent -> overlapped)
        const float w0 = Wp[(jp + 0) * 256];
        const float w1 = Wp[(jp + 1) * 256];
        const float w2 = Wp[(jp + 2) * 256];
        const float w3 = Wp[(jp + 3) * 256];
#pragma unroll
        for (int r = 0; r < ROWS; ++r) {
            const float4 s = *reinterpret_cast<const float4*>(&sv[r * 256 + jp]);  // ds_read_b128 broadcast
            acc[r] += s.x * w0 + s.y * w1 + s.z * w2 + s.w * w3;
        }
    }
#pragma unroll
    for (int r = 0; r < ROWS; ++r)
        out[(row0 + r) * 256 + j] = acc[r];
}

extern "C" void kernel_launch(void* const* d_in, const int* in_sizes, int n_in,
                              void* d_out, int out_size, void* d_ws, size_t ws_size,
                              hipStream_t stream) {
    // setup_inputs order: q(0) k(1) v(2) bias(3) atten_mask(4) Q(5) K(6) V(7)
    //                     bias_Q(8) bias_K(9) bias_V(10) linear_output(11)
    const float* v_in = (const float*)d_in[2];
    const float* V_w  = (const float*)d_in[7];
    const float* bV   = (const float*)d_in[10];
    const float* L    = (const float*)d_in[11];

    float* W2   = (float*)d_ws;           // 256*256 floats
    float* bvec = W2 + 256 * 256;         // 256 floats

    hipMemsetAsync(d_ws, 0, (256 * 256 + 256) * sizeof(float), stream);
    compose_w<<<dim3(16, 16), 256, 0, stream>>>(V_w, bV, L, W2, bvec);
    apply_w<<<4096 / ROWS, 256, 0, stream>>>(v_in, W2, bvec, (float*)d_out);
}